// Round 5
// baseline (371.729 us; speedup 1.0000x reference)
//
#include <hip/hip_runtime.h>

typedef __bf16 bf16;
typedef __bf16 bf16x8 __attribute__((ext_vector_type(8)));
typedef float  f32x4  __attribute__((ext_vector_type(4)));

#define NEG_INF (-__builtin_inff())
#define L2E 1.44269504088896f
#define DEFER_THR 5.545177444479562f   /* 8 / log2(e): exp2 exponent bound 8 */

// ---------------- conversion kernels (LDS-tile transpose) ----------------

// W_q/W_k/W_v [16][1024][64] fp32 -> hi/lo bf16 [3072][1024]; row n=proj*1024+h*64+k, col d
__global__ void k_cvt_wqkv(const float* __restrict__ wq, const float* __restrict__ wk,
                           const float* __restrict__ wv,
                           bf16* __restrict__ ohi, bf16* __restrict__ olo) {
    __shared__ float tile[64][65];
    const int d0 = blockIdx.x * 64, h = blockIdx.y, proj = blockIdx.z;
    const float* w = (proj == 0) ? wq : ((proj == 1) ? wk : wv);
    const int t = threadIdx.x;
    {
        int k = t & 63, dr = t >> 6;
        #pragma unroll
        for (int i = 0; i < 16; i++) {
            int dl = i * 4 + dr;
            tile[dl][k] = w[(size_t)(h * 1024 + d0 + dl) * 64 + k];
        }
    }
    __syncthreads();
    {
        int dl = t & 63, kr = t >> 6;
        #pragma unroll
        for (int i = 0; i < 16; i++) {
            int k = i * 4 + kr;
            float v = tile[dl][k];
            bf16 hi = (bf16)v;
            size_t o = (size_t)(proj * 1024 + h * 64 + k) * 1024 + d0 + dl;
            ohi[o] = hi;
            olo[o] = (bf16)(v - (float)hi);
        }
    }
}

// W_0 [1024][1024] -> w0t[n][c] = W_0[c][n]
__global__ void k_cvt_w0(const float* __restrict__ w0, bf16* __restrict__ out) {
    __shared__ float tile[64][65];
    const int n0 = blockIdx.x * 64, c0 = blockIdx.y * 64;
    const int t = threadIdx.x;
    {
        int n = t & 63, cr = t >> 6;
        #pragma unroll
        for (int i = 0; i < 16; i++) {
            int cl = i * 4 + cr;
            tile[cl][n] = w0[(size_t)(c0 + cl) * 1024 + n0 + n];
        }
    }
    __syncthreads();
    {
        int cl = t & 63, nr = t >> 6;
        #pragma unroll
        for (int i = 0; i < 16; i++) {
            int nl = i * 4 + nr;
            out[(size_t)(n0 + nl) * 1024 + c0 + cl] = (bf16)tile[cl][nl];
        }
    }
}

// ---------------- projection GEMM, Q/K only (split-bf16, 3-pass) ----------------
__global__ __launch_bounds__(256)
void k_gemm3(const float* __restrict__ A32,
             const bf16* __restrict__ Bhi, const bf16* __restrict__ Blo,
             bf16* __restrict__ Qhi, bf16* __restrict__ Qlo,
             bf16* __restrict__ Khi, bf16* __restrict__ Klo)
{
    __shared__ char Ash[128 * 128];
    __shared__ char Asl[128 * 128];
    __shared__ char Bsh[128 * 128];
    __shared__ char Bsl[128 * 128];
    const int t = threadIdx.x;
    const int m0 = blockIdx.x * 128;
    const int n0 = blockIdx.y * 128;
    const int wid = t >> 6, lane = t & 63, lr = lane & 15, lg = lane >> 4;
    const int wm = wid >> 1, wn = wid & 1;

    f32x4 acc[4][4] = {};

    for (int k0 = 0; k0 < 1024; k0 += 64) {
        #pragma unroll
        for (int i = 0; i < 4; i++) {
            int cid = t + i * 256;
            int r = cid >> 3, c8 = cid & 7;
            int sw = (c8 * 16) ^ ((r & 7) << 4);
            const float* ap = A32 + (size_t)(m0 + r) * 1024 + k0 + c8 * 8;
            float4 va = *reinterpret_cast<const float4*>(ap);
            float4 vb = *reinterpret_cast<const float4*>(ap + 4);
            float v[8] = {va.x, va.y, va.z, va.w, vb.x, vb.y, vb.z, vb.w};
            bf16x8 h8, l8;
            #pragma unroll
            for (int e = 0; e < 8; e++) {
                bf16 h = (bf16)v[e];
                h8[e] = h;
                l8[e] = (bf16)(v[e] - (float)h);
            }
            *reinterpret_cast<bf16x8*>(Ash + r * 128 + sw) = h8;
            *reinterpret_cast<bf16x8*>(Asl + r * 128 + sw) = l8;
            *reinterpret_cast<bf16x8*>(Bsh + r * 128 + sw) =
                *reinterpret_cast<const bf16x8*>(Bhi + (size_t)(n0 + r) * 1024 + k0 + c8 * 8);
            *reinterpret_cast<bf16x8*>(Bsl + r * 128 + sw) =
                *reinterpret_cast<const bf16x8*>(Blo + (size_t)(n0 + r) * 1024 + k0 + c8 * 8);
        }
        __syncthreads();
        #pragma unroll
        for (int kk = 0; kk < 2; kk++) {
            bf16x8 ah[4], al[4], bh[4], bl[4];
            #pragma unroll
            for (int mt = 0; mt < 4; mt++) {
                int row = wm * 64 + mt * 16 + lr;
                int off = row * 128 + (((kk * 4 + lg) * 16) ^ ((row & 7) << 4));
                ah[mt] = *reinterpret_cast<const bf16x8*>(Ash + off);
                al[mt] = *reinterpret_cast<const bf16x8*>(Asl + off);
            }
            #pragma unroll
            for (int nt = 0; nt < 4; nt++) {
                int row = wn * 64 + nt * 16 + lr;
                int off = row * 128 + (((kk * 4 + lg) * 16) ^ ((row & 7) << 4));
                bh[nt] = *reinterpret_cast<const bf16x8*>(Bsh + off);
                bl[nt] = *reinterpret_cast<const bf16x8*>(Bsl + off);
            }
            #pragma unroll
            for (int mt = 0; mt < 4; mt++)
                #pragma unroll
                for (int nt = 0; nt < 4; nt++) {
                    acc[mt][nt] = __builtin_amdgcn_mfma_f32_16x16x32_bf16(
                        ah[mt], bh[nt], acc[mt][nt], 0, 0, 0);
                    acc[mt][nt] = __builtin_amdgcn_mfma_f32_16x16x32_bf16(
                        ah[mt], bl[nt], acc[mt][nt], 0, 0, 0);
                    acc[mt][nt] = __builtin_amdgcn_mfma_f32_16x16x32_bf16(
                        al[mt], bh[nt], acc[mt][nt], 0, 0, 0);
                }
        }
        __syncthreads();
    }

    #pragma unroll
    for (int mt = 0; mt < 4; mt++)
        #pragma unroll
        for (int nt = 0; nt < 4; nt++)
            #pragma unroll
            for (int j = 0; j < 4; j++) {
                int m = m0 + wm * 64 + mt * 16 + lg * 4 + j;
                int n = n0 + wn * 64 + nt * 16 + lr;
                float v = acc[mt][nt][j];
                int b = m >> 11, s = m & 2047;
                if (n < 1024) {
                    int h = n >> 6, k = n & 63;
                    size_t idx = ((size_t)(b * 16 + h) * 2048 + s) * 64 + k;
                    float vs = v * 0.125f;
                    bf16 hi = (bf16)vs;
                    Qhi[idx] = hi;
                    Qlo[idx] = (bf16)(vs - (float)hi);
                } else {
                    int n2 = n - 1024, h = n2 >> 6, k = n2 & 63;
                    size_t idx = ((size_t)(b * 16 + h) * 2048 + s) * 64 + k;
                    bf16 hi = (bf16)v;
                    Khi[idx] = hi;
                    Klo[idx] = (bf16)(v - (float)hi);
                }
            }
}

// ---------------- projection GEMM, V only (single-pass bf16) ----------------
__global__ __launch_bounds__(256)
void k_gemmV(const float* __restrict__ A32, const bf16* __restrict__ Bhi,
             bf16* __restrict__ Vtb)
{
    __shared__ char As[128 * 128];
    __shared__ char Bs[128 * 128];
    const int t = threadIdx.x;
    const int m0 = blockIdx.x * 128;
    const int nb = blockIdx.y * 128;
    const int wid = t >> 6, lane = t & 63, lr = lane & 15, lg = lane >> 4;
    const int wm = wid >> 1, wn = wid & 1;

    f32x4 acc[4][4] = {};

    for (int k0 = 0; k0 < 1024; k0 += 64) {
        #pragma unroll
        for (int i = 0; i < 4; i++) {
            int cid = t + i * 256;
            int r = cid >> 3, c8 = cid & 7;
            int sw = (c8 * 16) ^ ((r & 7) << 4);
            const float* ap = A32 + (size_t)(m0 + r) * 1024 + k0 + c8 * 8;
            float4 va = *reinterpret_cast<const float4*>(ap);
            float4 vb = *reinterpret_cast<const float4*>(ap + 4);
            float v[8] = {va.x, va.y, va.z, va.w, vb.x, vb.y, vb.z, vb.w};
            bf16x8 h8;
            #pragma unroll
            for (int e = 0; e < 8; e++) h8[e] = (bf16)v[e];
            *reinterpret_cast<bf16x8*>(As + r * 128 + sw) = h8;
            *reinterpret_cast<bf16x8*>(Bs + r * 128 + sw) =
                *reinterpret_cast<const bf16x8*>(Bhi + (size_t)(2048 + nb + r) * 1024 + k0 + c8 * 8);
        }
        __syncthreads();
        #pragma unroll
        for (int kk = 0; kk < 2; kk++) {
            bf16x8 af[4], bfr[4];
            #pragma unroll
            for (int mt = 0; mt < 4; mt++) {
                int row = wm * 64 + mt * 16 + lr;
                af[mt] = *reinterpret_cast<const bf16x8*>(
                    As + row * 128 + (((kk * 4 + lg) * 16) ^ ((row & 7) << 4)));
            }
            #pragma unroll
            for (int nt = 0; nt < 4; nt++) {
                int row = wn * 64 + nt * 16 + lr;
                bfr[nt] = *reinterpret_cast<const bf16x8*>(
                    Bs + row * 128 + (((kk * 4 + lg) * 16) ^ ((row & 7) << 4)));
            }
            #pragma unroll
            for (int mt = 0; mt < 4; mt++)
                #pragma unroll
                for (int nt = 0; nt < 4; nt++)
                    acc[mt][nt] = __builtin_amdgcn_mfma_f32_16x16x32_bf16(
                        af[mt], bfr[nt], acc[mt][nt], 0, 0, 0);
        }
        __syncthreads();
    }

    #pragma unroll
    for (int mt = 0; mt < 4; mt++)
        #pragma unroll
        for (int nt = 0; nt < 4; nt++)
            #pragma unroll
            for (int j = 0; j < 4; j++) {
                int m = m0 + wm * 64 + mt * 16 + lg * 4 + j;
                int nl = nb + wn * 64 + nt * 16 + lr;
                int b = m >> 11, s = m & 2047;
                int h = nl >> 6, dv = nl & 63;
                Vtb[((size_t)(b * 16 + h) * 64 + dv) * 2048 + s] = (bf16)acc[mt][nt][j];
            }
}

// ---------------- output GEMM (single bf16) ----------------
__global__ __launch_bounds__(256)
void k_gemm1(const bf16* __restrict__ A, const bf16* __restrict__ Bt,
             float* __restrict__ Out)
{
    __shared__ char As[128 * 128];
    __shared__ char Bs[128 * 128];
    const int t = threadIdx.x;
    const int m0 = blockIdx.x * 128;
    const int n0 = blockIdx.y * 128;
    const int wid = t >> 6, lane = t & 63, lr = lane & 15, lg = lane >> 4;
    const int wm = wid >> 1, wn = wid & 1;

    f32x4 acc[4][4] = {};

    for (int k0 = 0; k0 < 1024; k0 += 64) {
        #pragma unroll
        for (int i = 0; i < 4; i++) {
            int cid = t + i * 256;
            int r = cid >> 3, c8 = cid & 7;
            int sw = (c8 * 16) ^ ((r & 7) << 4);
            *reinterpret_cast<bf16x8*>(As + r * 128 + sw) =
                *reinterpret_cast<const bf16x8*>(A + (size_t)(m0 + r) * 1024 + k0 + c8 * 8);
            *reinterpret_cast<bf16x8*>(Bs + r * 128 + sw) =
                *reinterpret_cast<const bf16x8*>(Bt + (size_t)(n0 + r) * 1024 + k0 + c8 * 8);
        }
        __syncthreads();
        #pragma unroll
        for (int kk = 0; kk < 2; kk++) {
            bf16x8 af[4], bfr[4];
            #pragma unroll
            for (int mt = 0; mt < 4; mt++) {
                int row = wm * 64 + mt * 16 + lr;
                af[mt] = *reinterpret_cast<const bf16x8*>(
                    As + row * 128 + (((kk * 4 + lg) * 16) ^ ((row & 7) << 4)));
            }
            #pragma unroll
            for (int nt = 0; nt < 4; nt++) {
                int row = wn * 64 + nt * 16 + lr;
                bfr[nt] = *reinterpret_cast<const bf16x8*>(
                    Bs + row * 128 + (((kk * 4 + lg) * 16) ^ ((row & 7) << 4)));
            }
            #pragma unroll
            for (int mt = 0; mt < 4; mt++)
                #pragma unroll
                for (int nt = 0; nt < 4; nt++)
                    acc[mt][nt] = __builtin_amdgcn_mfma_f32_16x16x32_bf16(
                        af[mt], bfr[nt], acc[mt][nt], 0, 0, 0);
        }
        __syncthreads();
    }

    #pragma unroll
    for (int mt = 0; mt < 4; mt++)
        #pragma unroll
        for (int nt = 0; nt < 4; nt++)
            #pragma unroll
            for (int j = 0; j < 4; j++) {
                int m = m0 + wm * 64 + mt * 16 + lg * 4 + j;
                int n = n0 + wn * 64 + nt * 16 + lr;
                Out[(size_t)m * 1024 + n] = acc[mt][nt][j];
            }
}

// ---------------- flash attention v4 ----------------
// 1024 blocks x 512 threads (8 waves). QBLK=128 (16 q-rows/wave), KVBLK=64.
// Double-buffered K/V LDS (one barrier/iter); deferred-sum softmax (cross-lane
// reduce once at end); defer-max via ballot (T13); s_setprio around MFMA (T5).
__global__ __launch_bounds__(512)
void k_attn(const bf16* __restrict__ Qhi, const bf16* __restrict__ Qlo,
            const bf16* __restrict__ Khi, const bf16* __restrict__ Klo,
            const bf16* __restrict__ Vtb, bf16* __restrict__ hd)
{
    __shared__ char Ksh[2][64 * 128];
    __shared__ char Ksl[2][64 * 128];
    __shared__ char Vs[2][64 * 128];
    __shared__ char Ps[8 * 2048];
    const int bid = blockIdx.x;
    const int swz = (bid & 7) * 128 + (bid >> 3);
    const int bh = swz >> 4, qB = 15 - (swz & 15);
    const int t = threadIdx.x, wid = t >> 6, lane = t & 63, lr = lane & 15, lg = lane >> 4;
    const bf16* Qhp = Qhi + (size_t)bh * 131072;
    const bf16* Qlp = Qlo + (size_t)bh * 131072;
    const bf16* Khp = Khi + (size_t)bh * 131072;
    const bf16* Klp = Klo + (size_t)bh * 131072;
    const bf16* Vp  = Vtb + (size_t)bh * 131072;
    const int q0 = qB * 128 + wid * 16;
    const int qdiv = q0 >> 6;          // kb with triangle mask; kb>qdiv fully masked
    const int kbmax = 2 * qB + 1;

    // Q fragments (hi/lo)
    bf16x8 qh[2], ql[2];
    #pragma unroll
    for (int kk = 0; kk < 2; kk++) {
        size_t off = (size_t)(q0 + lr) * 64 + kk * 32 + lg * 8;
        qh[kk] = *reinterpret_cast<const bf16x8*>(Qhp + off);
        ql[kk] = *reinterpret_cast<const bf16x8*>(Qlp + off);
    }

    // staging geometry: 512 threads cover one 64x(64bf16) plane exactly
    const int r = t >> 3, c8 = t & 7;
    const int sw = (c8 * 16) ^ ((r & 7) << 4);

    // prologue: stage tile 0 into buf 0
    {
        bf16x8 a = *reinterpret_cast<const bf16x8*>(Khp + (size_t)r * 64 + c8 * 8);
        bf16x8 b = *reinterpret_cast<const bf16x8*>(Klp + (size_t)r * 64 + c8 * 8);
        bf16x8 c = *reinterpret_cast<const bf16x8*>(Vp + (size_t)r * 2048 + c8 * 8);
        *reinterpret_cast<bf16x8*>(Ksh[0] + r * 128 + sw) = a;
        *reinterpret_cast<bf16x8*>(Ksl[0] + r * 128 + sw) = b;
        *reinterpret_cast<bf16x8*>(Vs[0] + r * 128 + sw) = c;
    }
    __syncthreads();

    f32x4 accO[4] = {};
    float mrow[4] = {NEG_INF, NEG_INF, NEG_INF, NEG_INF};
    float lsum[4] = {};

    for (int kb = 0; kb <= kbmax; kb++) {
        const int cur = kb & 1, nxt = cur ^ 1;
        // prefetch next tile into registers (T14)
        bf16x8 pkh, pkl, pv;
        if (kb < kbmax) {
            size_t kbase = (size_t)(kb + 1) * 4096;
            int vcol = (kb + 1) * 64;
            pkh = *reinterpret_cast<const bf16x8*>(Khp + kbase + (size_t)r * 64 + c8 * 8);
            pkl = *reinterpret_cast<const bf16x8*>(Klp + kbase + (size_t)r * 64 + c8 * 8);
            pv  = *reinterpret_cast<const bf16x8*>(Vp + (size_t)r * 2048 + vcol + c8 * 8);
        }

        if (kb <= qdiv) {   // this wave's tile not fully masked
            // ---- QK^T (3-pass split-bf16) ----
            f32x4 sc[4] = {};
            __builtin_amdgcn_s_setprio(1);
            #pragma unroll
            for (int kk = 0; kk < 2; kk++) {
                bf16x8 bh8[4], bl8[4];
                #pragma unroll
                for (int nt = 0; nt < 4; nt++) {
                    int row = nt * 16 + lr;
                    int off = row * 128 + (((kk * 4 + lg) * 16) ^ ((row & 7) << 4));
                    bh8[nt] = *reinterpret_cast<const bf16x8*>(Ksh[cur] + off);
                    bl8[nt] = *reinterpret_cast<const bf16x8*>(Ksl[cur] + off);
                }
                #pragma unroll
                for (int nt = 0; nt < 4; nt++) {
                    sc[nt] = __builtin_amdgcn_mfma_f32_16x16x32_bf16(qh[kk], bh8[nt], sc[nt], 0, 0, 0);
                    sc[nt] = __builtin_amdgcn_mfma_f32_16x16x32_bf16(qh[kk], bl8[nt], sc[nt], 0, 0, 0);
                    sc[nt] = __builtin_amdgcn_mfma_f32_16x16x32_bf16(ql[kk], bh8[nt], sc[nt], 0, 0, 0);
                }
            }
            __builtin_amdgcn_s_setprio(0);

            if (kb == qdiv) {
                #pragma unroll
                for (int nt = 0; nt < 4; nt++)
                    #pragma unroll
                    for (int j = 0; j < 4; j++) {
                        int kg = kb * 64 + nt * 16 + lr;
                        int qg = q0 + lg * 4 + j;
                        if (kg > qg) sc[nt][j] = NEG_INF;
                    }
            }

            // ---- online softmax: defer-max (ballot), deferred sum ----
            float lm[4];
            #pragma unroll
            for (int j = 0; j < 4; j++)
                lm[j] = fmaxf(fmaxf(sc[0][j], sc[1][j]), fmaxf(sc[2][j], sc[3][j]));
            bool grow = (lm[0] > mrow[0] + DEFER_THR) | (lm[1] > mrow[1] + DEFER_THR) |
                        (lm[2] > mrow[2] + DEFER_THR) | (lm[3] > mrow[3] + DEFER_THR);
            if (__any(grow)) {
                #pragma unroll
                for (int j = 0; j < 4; j++) {
                    float pm = lm[j];
                    #pragma unroll
                    for (int off = 1; off < 16; off <<= 1)
                        pm = fmaxf(pm, __shfl_xor(pm, off));
                    float mnew = fmaxf(mrow[j], pm);
                    float alpha = exp2f((mrow[j] - mnew) * L2E);
                    mrow[j] = mnew;
                    lsum[j] *= alpha;
                    accO[0][j] *= alpha; accO[1][j] *= alpha;
                    accO[2][j] *= alpha; accO[3][j] *= alpha;
                }
            }
            #pragma unroll
            for (int nt = 0; nt < 4; nt++)
                #pragma unroll
                for (int j = 0; j < 4; j++)
                    sc[nt][j] = exp2f((sc[nt][j] - mrow[j]) * L2E);
            #pragma unroll
            for (int j = 0; j < 4; j++)
                lsum[j] += (sc[0][j] + sc[1][j]) + (sc[2][j] + sc[3][j]);

            // ---- P -> per-wave LDS (transpose to A-fragment layout) ----
            char* Pw = Ps + wid * 2048;
            #pragma unroll
            for (int nt = 0; nt < 4; nt++)
                #pragma unroll
                for (int j = 0; j < 4; j++) {
                    int rr = lg * 4 + j, c = nt * 16 + lr;
                    *reinterpret_cast<bf16*>(Pw + rr * 128 + ((2 * c) ^ ((rr & 7) << 4))) =
                        (bf16)sc[nt][j];
                }
            bf16x8 ap[2];
            #pragma unroll
            for (int kk = 0; kk < 2; kk++)
                ap[kk] = *reinterpret_cast<const bf16x8*>(
                    Pw + lr * 128 + (((kk * 4 + lg) * 16) ^ ((lr & 7) << 4)));

            // ---- PV ----
            __builtin_amdgcn_s_setprio(1);
            #pragma unroll
            for (int kk = 0; kk < 2; kk++)
                #pragma unroll
                for (int nt = 0; nt < 4; nt++) {
                    int row = nt * 16 + lr;
                    bf16x8 bv = *reinterpret_cast<const bf16x8*>(
                        Vs[cur] + row * 128 + (((kk * 4 + lg) * 16) ^ ((row & 7) << 4)));
                    accO[nt] = __builtin_amdgcn_mfma_f32_16x16x32_bf16(ap[kk], bv, accO[nt], 0, 0, 0);
                }
            __builtin_amdgcn_s_setprio(0);
        }

        // ---- write prefetched tile into next buffer; single barrier ----
        if (kb < kbmax) {
            *reinterpret_cast<bf16x8*>(Ksh[nxt] + r * 128 + sw) = pkh;
            *reinterpret_cast<bf16x8*>(Ksl[nxt] + r * 128 + sw) = pkl;
            *reinterpret_cast<bf16x8*>(Vs[nxt] + r * 128 + sw) = pv;
        }
        __syncthreads();
    }

    // final cross-lane sum reduce (once per kernel)
    #pragma unroll
    for (int j = 0; j < 4; j++) {
        float ps = lsum[j];
        #pragma unroll
        for (int off = 1; off < 16; off <<= 1)
            ps += __shfl_xor(ps, off);
        float inv = 1.0f / ps;
        int qg = q0 + lg * 4 + j;
        #pragma unroll
        for (int nt = 0; nt < 4; nt++) {
            int col = (bh & 15) * 64 + nt * 16 + lr;
            hd[(size_t)((bh >> 4) * 2048 + qg) * 1024 + col] = (bf16)(accO[nt][j] * inv);
        }
    }
}

// ---------------- launcher ----------------

extern "C" void kernel_launch(void* const* d_in, const int* in_sizes, int n_in,
                              void* d_out, int out_size, void* d_ws, size_t ws_size,
                              hipStream_t stream) {
    const float* x  = (const float*)d_in[0];
    const float* Wq = (const float*)d_in[1];
    const float* Wk = (const float*)d_in[2];
    const float* Wv = (const float*)d_in[3];
    const float* W0 = (const float*)d_in[4];
    float* out = (float*)d_out;

    char* ws = (char*)d_ws;
    bf16* w0t = (bf16*)(ws + 0);
    bf16* Qhi = (bf16*)(ws + 2097152);
    bf16* Qlo = (bf16*)(ws + 18874368);
    bf16* Khi = (bf16*)(ws + 35651584);
    bf16* Klo = (bf16*)(ws + 52428800);
    bf16* Vtb = (bf16*)(ws + 69206016);
    bf16* whi = (bf16*)(ws + 85983232);
    bf16* wlo = (bf16*)(ws + 92274688);
    bf16* hd  = (bf16*)(ws + 85983232);
    if (ws_size < 102760448u) return;  // need 98 MiB scratch

    k_cvt_wqkv<<<dim3(16, 16, 3), 256, 0, stream>>>(Wq, Wk, Wv, whi, wlo);
    k_cvt_w0  <<<dim3(16, 16), 256, 0, stream>>>(W0, w0t);
    k_gemm3   <<<dim3(64, 16), 256, 0, stream>>>(x, whi, wlo, Qhi, Qlo, Khi, Klo);
    k_gemmV   <<<dim3(64, 8), 256, 0, stream>>>(x, whi, Vtb);
    k_attn    <<<1024, 512, 0, stream>>>(Qhi, Qlo, Khi, Klo, Vtb, hd);
    k_gemm1   <<<dim3(64, 8), 256, 0, stream>>>(hd, w0t, out);
}

// Round 6
// 304.539 us; speedup vs baseline: 1.2206x; 1.2206x over previous
//
#include <hip/hip_runtime.h>

typedef __bf16 bf16;
typedef __bf16 bf16x4 __attribute__((ext_vector_type(4)));
typedef __bf16 bf16x8 __attribute__((ext_vector_type(8)));
typedef float  f32x4  __attribute__((ext_vector_type(4)));

#define NEG_INF (-__builtin_inff())
#define L2E 1.44269504088896f
#define DEFER_THR 5.545177444479562f   /* 8 / log2(e): exp2 exponent bound 8 */

// ---------------- conversion kernels (LDS-tile transpose) ----------------

__global__ void k_cvt_wqkv(const float* __restrict__ wq, const float* __restrict__ wk,
                           const float* __restrict__ wv,
                           bf16* __restrict__ ohi, bf16* __restrict__ olo) {
    __shared__ float tile[64][65];
    const int d0 = blockIdx.x * 64, h = blockIdx.y, proj = blockIdx.z;
    const float* w = (proj == 0) ? wq : ((proj == 1) ? wk : wv);
    const int t = threadIdx.x;
    {
        int k = t & 63, dr = t >> 6;
        #pragma unroll
        for (int i = 0; i < 16; i++) {
            int dl = i * 4 + dr;
            tile[dl][k] = w[(size_t)(h * 1024 + d0 + dl) * 64 + k];
        }
    }
    __syncthreads();
    {
        int dl = t & 63, kr = t >> 6;
        #pragma unroll
        for (int i = 0; i < 16; i++) {
            int k = i * 4 + kr;
            float v = tile[dl][k];
            bf16 hi = (bf16)v;
            size_t o = (size_t)(proj * 1024 + h * 64 + k) * 1024 + d0 + dl;
            ohi[o] = hi;
            olo[o] = (bf16)(v - (float)hi);
        }
    }
}

__global__ void k_cvt_w0(const float* __restrict__ w0, bf16* __restrict__ out) {
    __shared__ float tile[64][65];
    const int n0 = blockIdx.x * 64, c0 = blockIdx.y * 64;
    const int t = threadIdx.x;
    {
        int n = t & 63, cr = t >> 6;
        #pragma unroll
        for (int i = 0; i < 16; i++) {
            int cl = i * 4 + cr;
            tile[cl][n] = w0[(size_t)(c0 + cl) * 1024 + n0 + n];
        }
    }
    __syncthreads();
    {
        int cl = t & 63, nr = t >> 6;
        #pragma unroll
        for (int i = 0; i < 16; i++) {
            int nl = i * 4 + nr;
            out[(size_t)(n0 + nl) * 1024 + c0 + cl] = (bf16)tile[cl][nl];
        }
    }
}

// ---------------- projection GEMM, Q/K only (split-bf16, 3-pass) ----------------
__global__ __launch_bounds__(256)
void k_gemm3(const float* __restrict__ A32,
             const bf16* __restrict__ Bhi, const bf16* __restrict__ Blo,
             bf16* __restrict__ Qhi, bf16* __restrict__ Qlo,
             bf16* __restrict__ Khi, bf16* __restrict__ Klo)
{
    __shared__ char Ash[128 * 128];
    __shared__ char Asl[128 * 128];
    __shared__ char Bsh[128 * 128];
    __shared__ char Bsl[128 * 128];
    const int t = threadIdx.x;
    const int m0 = blockIdx.x * 128;
    const int n0 = blockIdx.y * 128;
    const int wid = t >> 6, lane = t & 63, lr = lane & 15, lg = lane >> 4;
    const int wm = wid >> 1, wn = wid & 1;

    f32x4 acc[4][4] = {};

    for (int k0 = 0; k0 < 1024; k0 += 64) {
        #pragma unroll
        for (int i = 0; i < 4; i++) {
            int cid = t + i * 256;
            int r = cid >> 3, c8 = cid & 7;
            int sw = (c8 * 16) ^ ((r & 7) << 4);
            const float* ap = A32 + (size_t)(m0 + r) * 1024 + k0 + c8 * 8;
            float4 va = *reinterpret_cast<const float4*>(ap);
            float4 vb = *reinterpret_cast<const float4*>(ap + 4);
            float v[8] = {va.x, va.y, va.z, va.w, vb.x, vb.y, vb.z, vb.w};
            bf16x8 h8, l8;
            #pragma unroll
            for (int e = 0; e < 8; e++) {
                bf16 h = (bf16)v[e];
                h8[e] = h;
                l8[e] = (bf16)(v[e] - (float)h);
            }
            *reinterpret_cast<bf16x8*>(Ash + r * 128 + sw) = h8;
            *reinterpret_cast<bf16x8*>(Asl + r * 128 + sw) = l8;
            *reinterpret_cast<bf16x8*>(Bsh + r * 128 + sw) =
                *reinterpret_cast<const bf16x8*>(Bhi + (size_t)(n0 + r) * 1024 + k0 + c8 * 8);
            *reinterpret_cast<bf16x8*>(Bsl + r * 128 + sw) =
                *reinterpret_cast<const bf16x8*>(Blo + (size_t)(n0 + r) * 1024 + k0 + c8 * 8);
        }
        __syncthreads();
        #pragma unroll
        for (int kk = 0; kk < 2; kk++) {
            bf16x8 ah[4], al[4], bh[4], bl[4];
            #pragma unroll
            for (int mt = 0; mt < 4; mt++) {
                int row = wm * 64 + mt * 16 + lr;
                int off = row * 128 + (((kk * 4 + lg) * 16) ^ ((row & 7) << 4));
                ah[mt] = *reinterpret_cast<const bf16x8*>(Ash + off);
                al[mt] = *reinterpret_cast<const bf16x8*>(Asl + off);
            }
            #pragma unroll
            for (int nt = 0; nt < 4; nt++) {
                int row = wn * 64 + nt * 16 + lr;
                int off = row * 128 + (((kk * 4 + lg) * 16) ^ ((row & 7) << 4));
                bh[nt] = *reinterpret_cast<const bf16x8*>(Bsh + off);
                bl[nt] = *reinterpret_cast<const bf16x8*>(Bsl + off);
            }
            #pragma unroll
            for (int mt = 0; mt < 4; mt++)
                #pragma unroll
                for (int nt = 0; nt < 4; nt++) {
                    acc[mt][nt] = __builtin_amdgcn_mfma_f32_16x16x32_bf16(
                        ah[mt], bh[nt], acc[mt][nt], 0, 0, 0);
                    acc[mt][nt] = __builtin_amdgcn_mfma_f32_16x16x32_bf16(
                        ah[mt], bl[nt], acc[mt][nt], 0, 0, 0);
                    acc[mt][nt] = __builtin_amdgcn_mfma_f32_16x16x32_bf16(
                        al[mt], bh[nt], acc[mt][nt], 0, 0, 0);
                }
        }
        __syncthreads();
    }

    #pragma unroll
    for (int mt = 0; mt < 4; mt++)
        #pragma unroll
        for (int nt = 0; nt < 4; nt++)
            #pragma unroll
            for (int j = 0; j < 4; j++) {
                int m = m0 + wm * 64 + mt * 16 + lg * 4 + j;
                int n = n0 + wn * 64 + nt * 16 + lr;
                float v = acc[mt][nt][j];
                int b = m >> 11, s = m & 2047;
                if (n < 1024) {
                    int h = n >> 6, k = n & 63;
                    size_t idx = ((size_t)(b * 16 + h) * 2048 + s) * 64 + k;
                    float vs = v * 0.125f;
                    bf16 hi = (bf16)vs;
                    Qhi[idx] = hi;
                    Qlo[idx] = (bf16)(vs - (float)hi);
                } else {
                    int n2 = n - 1024, h = n2 >> 6, k = n2 & 63;
                    size_t idx = ((size_t)(b * 16 + h) * 2048 + s) * 64 + k;
                    bf16 hi = (bf16)v;
                    Khi[idx] = hi;
                    Klo[idx] = (bf16)(v - (float)hi);
                }
            }
}

// ---------------- projection GEMM, V only (single-pass bf16) ----------------
__global__ __launch_bounds__(256)
void k_gemmV(const float* __restrict__ A32, const bf16* __restrict__ Bhi,
             bf16* __restrict__ Vtb)
{
    __shared__ char As[128 * 128];
    __shared__ char Bs[128 * 128];
    const int t = threadIdx.x;
    const int m0 = blockIdx.x * 128;
    const int nb = blockIdx.y * 128;
    const int wid = t >> 6, lane = t & 63, lr = lane & 15, lg = lane >> 4;
    const int wm = wid >> 1, wn = wid & 1;

    f32x4 acc[4][4] = {};

    for (int k0 = 0; k0 < 1024; k0 += 64) {
        #pragma unroll
        for (int i = 0; i < 4; i++) {
            int cid = t + i * 256;
            int r = cid >> 3, c8 = cid & 7;
            int sw = (c8 * 16) ^ ((r & 7) << 4);
            const float* ap = A32 + (size_t)(m0 + r) * 1024 + k0 + c8 * 8;
            float4 va = *reinterpret_cast<const float4*>(ap);
            float4 vb = *reinterpret_cast<const float4*>(ap + 4);
            float v[8] = {va.x, va.y, va.z, va.w, vb.x, vb.y, vb.z, vb.w};
            bf16x8 h8;
            #pragma unroll
            for (int e = 0; e < 8; e++) h8[e] = (bf16)v[e];
            *reinterpret_cast<bf16x8*>(As + r * 128 + sw) = h8;
            *reinterpret_cast<bf16x8*>(Bs + r * 128 + sw) =
                *reinterpret_cast<const bf16x8*>(Bhi + (size_t)(2048 + nb + r) * 1024 + k0 + c8 * 8);
        }
        __syncthreads();
        #pragma unroll
        for (int kk = 0; kk < 2; kk++) {
            bf16x8 af[4], bfr[4];
            #pragma unroll
            for (int mt = 0; mt < 4; mt++) {
                int row = wm * 64 + mt * 16 + lr;
                af[mt] = *reinterpret_cast<const bf16x8*>(
                    As + row * 128 + (((kk * 4 + lg) * 16) ^ ((row & 7) << 4)));
            }
            #pragma unroll
            for (int nt = 0; nt < 4; nt++) {
                int row = wn * 64 + nt * 16 + lr;
                bfr[nt] = *reinterpret_cast<const bf16x8*>(
                    Bs + row * 128 + (((kk * 4 + lg) * 16) ^ ((row & 7) << 4)));
            }
            #pragma unroll
            for (int mt = 0; mt < 4; mt++)
                #pragma unroll
                for (int nt = 0; nt < 4; nt++)
                    acc[mt][nt] = __builtin_amdgcn_mfma_f32_16x16x32_bf16(
                        af[mt], bfr[nt], acc[mt][nt], 0, 0, 0);
        }
        __syncthreads();
    }

    #pragma unroll
    for (int mt = 0; mt < 4; mt++)
        #pragma unroll
        for (int nt = 0; nt < 4; nt++)
            #pragma unroll
            for (int j = 0; j < 4; j++) {
                int m = m0 + wm * 64 + mt * 16 + lg * 4 + j;
                int nl = nb + wn * 64 + nt * 16 + lr;
                int b = m >> 11, s = m & 2047;
                int h = nl >> 6, dv = nl & 63;
                Vtb[((size_t)(b * 16 + h) * 64 + dv) * 2048 + s] = (bf16)acc[mt][nt][j];
            }
}

// ---------------- output GEMM (single bf16) ----------------
__global__ __launch_bounds__(256)
void k_gemm1(const bf16* __restrict__ A, const bf16* __restrict__ Bt,
             float* __restrict__ Out)
{
    __shared__ char As[128 * 128];
    __shared__ char Bs[128 * 128];
    const int t = threadIdx.x;
    const int m0 = blockIdx.x * 128;
    const int n0 = blockIdx.y * 128;
    const int wid = t >> 6, lane = t & 63, lr = lane & 15, lg = lane >> 4;
    const int wm = wid >> 1, wn = wid & 1;

    f32x4 acc[4][4] = {};

    for (int k0 = 0; k0 < 1024; k0 += 64) {
        #pragma unroll
        for (int i = 0; i < 4; i++) {
            int cid = t + i * 256;
            int r = cid >> 3, c8 = cid & 7;
            int sw = (c8 * 16) ^ ((r & 7) << 4);
            *reinterpret_cast<bf16x8*>(As + r * 128 + sw) =
                *reinterpret_cast<const bf16x8*>(A + (size_t)(m0 + r) * 1024 + k0 + c8 * 8);
            *reinterpret_cast<bf16x8*>(Bs + r * 128 + sw) =
                *reinterpret_cast<const bf16x8*>(Bt + (size_t)(n0 + r) * 1024 + k0 + c8 * 8);
        }
        __syncthreads();
        #pragma unroll
        for (int kk = 0; kk < 2; kk++) {
            bf16x8 af[4], bfr[4];
            #pragma unroll
            for (int mt = 0; mt < 4; mt++) {
                int row = wm * 64 + mt * 16 + lr;
                af[mt] = *reinterpret_cast<const bf16x8*>(
                    As + row * 128 + (((kk * 4 + lg) * 16) ^ ((row & 7) << 4)));
            }
            #pragma unroll
            for (int nt = 0; nt < 4; nt++) {
                int row = wn * 64 + nt * 16 + lr;
                bfr[nt] = *reinterpret_cast<const bf16x8*>(
                    Bs + row * 128 + (((kk * 4 + lg) * 16) ^ ((row & 7) << 4)));
            }
            #pragma unroll
            for (int mt = 0; mt < 4; mt++)
                #pragma unroll
                for (int nt = 0; nt < 4; nt++)
                    acc[mt][nt] = __builtin_amdgcn_mfma_f32_16x16x32_bf16(
                        af[mt], bfr[nt], acc[mt][nt], 0, 0, 0);
        }
        __syncthreads();
    }

    #pragma unroll
    for (int mt = 0; mt < 4; mt++)
        #pragma unroll
        for (int nt = 0; nt < 4; nt++)
            #pragma unroll
            for (int j = 0; j < 4; j++) {
                int m = m0 + wm * 64 + mt * 16 + lg * 4 + j;
                int n = n0 + wn * 64 + nt * 16 + lr;
                Out[(size_t)m * 1024 + n] = acc[mt][nt][j];
            }
}

// ---------------- flash attention v5: swapped QK^T, in-register softmax ----------------
// 1024 blocks x 512 threads (8 waves). QBLK=128 (16 q-rows/wave), KVBLK=64.
// S^T = mfma(K_frag, Q_frag): lane holds one q-row (q=lane&15), 16 k-values.
// Softmax state scalar per lane; P^T -> PV B-fragment via cvt_pk + permlane swaps
// (no LDS P roundtrip). Single-buffered K/V LDS (24 KB), T14 reg prefetch.
__global__ __launch_bounds__(512)
void k_attn(const bf16* __restrict__ Qhi, const bf16* __restrict__ Qlo,
            const bf16* __restrict__ Khi, const bf16* __restrict__ Klo,
            const bf16* __restrict__ Vtb, bf16* __restrict__ hd)
{
    __shared__ char Ksh[64 * 128];
    __shared__ char Ksl[64 * 128];
    __shared__ char Vs[64 * 128];
    const int bid = blockIdx.x;
    const int swz = (bid & 7) * 128 + (bid >> 3);
    const int bh = swz >> 4, qB = 15 - (swz & 15);
    const int t = threadIdx.x, wid = t >> 6, lane = t & 63, lr = lane & 15, lg = lane >> 4;
    const bf16* Qhp = Qhi + (size_t)bh * 131072;
    const bf16* Qlp = Qlo + (size_t)bh * 131072;
    const bf16* Khp = Khi + (size_t)bh * 131072;
    const bf16* Klp = Klo + (size_t)bh * 131072;
    const bf16* Vp  = Vtb + (size_t)bh * 131072;
    const int q0 = qB * 128 + wid * 16;
    const int qdiv = q0 >> 6;
    const int kbmax = 2 * qB + 1;
    const int qg = q0 + lr;            // this lane's q-row

    // Q fragments (hi/lo): row=q0+lr, d = kk*32 + lg*8 + e
    bf16x8 qh[2], ql[2];
    #pragma unroll
    for (int kk = 0; kk < 2; kk++) {
        size_t off = (size_t)(q0 + lr) * 64 + kk * 32 + lg * 8;
        qh[kk] = *reinterpret_cast<const bf16x8*>(Qhp + off);
        ql[kk] = *reinterpret_cast<const bf16x8*>(Qlp + off);
    }

    // staging geometry: 512 threads cover one 64x(64bf16) plane exactly
    const int r = t >> 3, c8 = t & 7;
    const int sw = (c8 * 16) ^ ((r & 7) << 4);

    {
        bf16x8 a = *reinterpret_cast<const bf16x8*>(Khp + (size_t)r * 64 + c8 * 8);
        bf16x8 b = *reinterpret_cast<const bf16x8*>(Klp + (size_t)r * 64 + c8 * 8);
        bf16x8 c = *reinterpret_cast<const bf16x8*>(Vp + (size_t)r * 2048 + c8 * 8);
        *reinterpret_cast<bf16x8*>(Ksh + r * 128 + sw) = a;
        *reinterpret_cast<bf16x8*>(Ksl + r * 128 + sw) = b;
        *reinterpret_cast<bf16x8*>(Vs + r * 128 + sw) = c;
    }
    __syncthreads();

    f32x4 accO[4] = {};                 // O^T frag: accO[nt][j] = O^T[dv=nt*16+4lg+j][q=lr]
    float mrow = NEG_INF;               // per-lane scalar (one q-row)
    float lsum = 0.0f;

    for (int kb = 0; kb <= kbmax; kb++) {
        // prefetch next tile into registers (T14)
        bf16x8 pkh, pkl, pv;
        if (kb < kbmax) {
            size_t kbase = (size_t)(kb + 1) * 4096;
            int vcol = (kb + 1) * 64;
            pkh = *reinterpret_cast<const bf16x8*>(Khp + kbase + (size_t)r * 64 + c8 * 8);
            pkl = *reinterpret_cast<const bf16x8*>(Klp + kbase + (size_t)r * 64 + c8 * 8);
            pv  = *reinterpret_cast<const bf16x8*>(Vp + (size_t)r * 2048 + vcol + c8 * 8);
        }

        if (kb <= qdiv) {
            // ---- S^T = K·Q^T (3-pass split-bf16), swapped operands ----
            // sc[nt][j] = S^T[k = kb*64 + nt*16 + 4lg + j][q = lr]
            f32x4 sc[4] = {};
            __builtin_amdgcn_s_setprio(1);
            #pragma unroll
            for (int kk = 0; kk < 2; kk++) {
                bf16x8 bh8[4], bl8[4];
                #pragma unroll
                for (int nt = 0; nt < 4; nt++) {
                    int row = nt * 16 + lr;
                    int off = row * 128 + (((kk * 4 + lg) * 16) ^ ((row & 7) << 4));
                    bh8[nt] = *reinterpret_cast<const bf16x8*>(Ksh + off);
                    bl8[nt] = *reinterpret_cast<const bf16x8*>(Ksl + off);
                }
                #pragma unroll
                for (int nt = 0; nt < 4; nt++) {
                    sc[nt] = __builtin_amdgcn_mfma_f32_16x16x32_bf16(bh8[nt], qh[kk], sc[nt], 0, 0, 0);
                    sc[nt] = __builtin_amdgcn_mfma_f32_16x16x32_bf16(bl8[nt], qh[kk], sc[nt], 0, 0, 0);
                    sc[nt] = __builtin_amdgcn_mfma_f32_16x16x32_bf16(bh8[nt], ql[kk], sc[nt], 0, 0, 0);
                }
            }
            __builtin_amdgcn_s_setprio(0);

            if (kb == qdiv) {
                #pragma unroll
                for (int nt = 0; nt < 4; nt++)
                    #pragma unroll
                    for (int j = 0; j < 4; j++) {
                        int kg = kb * 64 + nt * 16 + 4 * lg + j;
                        if (kg > qg) sc[nt][j] = NEG_INF;
                    }
            }

            // ---- online softmax (per-lane scalar state, defer-max) ----
            float lm = sc[0][0];
            #pragma unroll
            for (int nt = 0; nt < 4; nt++)
                #pragma unroll
                for (int j = 0; j < 4; j++)
                    lm = fmaxf(lm, sc[nt][j]);
            if (__any(lm > mrow + DEFER_THR)) {
                float pm = lm;
                pm = fmaxf(pm, __shfl_xor(pm, 16));
                pm = fmaxf(pm, __shfl_xor(pm, 32));
                float mnew = fmaxf(mrow, pm);
                float alpha = exp2f((mrow - mnew) * L2E);
                mrow = mnew;
                lsum *= alpha;
                #pragma unroll
                for (int nt = 0; nt < 4; nt++)
                    #pragma unroll
                    for (int j = 0; j < 4; j++)
                        accO[nt][j] *= alpha;
            }
            float tsum = 0.0f;
            #pragma unroll
            for (int nt = 0; nt < 4; nt++)
                #pragma unroll
                for (int j = 0; j < 4; j++) {
                    float e = exp2f((sc[nt][j] - mrow) * L2E);
                    sc[nt][j] = e;
                    tsum += e;
                }
            lsum += tsum;

            // ---- P^T -> B-fragments in-register (cvt_pk + permlane swaps) ----
            // w[nt][p] packs (sc[nt][2p], sc[nt][2p+1]); (A_p,B_p)=pl16(pl32(w[2kk][p],w[2kk+1][p]))
            unsigned int w[4][2];
            #pragma unroll
            for (int nt = 0; nt < 4; nt++)
                #pragma unroll
                for (int p = 0; p < 2; p++) {
                    unsigned int d;
                    asm("v_cvt_pk_bf16_f32 %0, %1, %2"
                        : "=v"(d) : "v"(sc[nt][2 * p]), "v"(sc[nt][2 * p + 1]));
                    w[nt][p] = d;
                }
            bf16x8 bp[2];
            #pragma unroll
            for (int kk = 0; kk < 2; kk++) {
                unsigned int a0 = w[2 * kk][0], b0 = w[2 * kk + 1][0];
                unsigned int a1 = w[2 * kk][1], b1 = w[2 * kk + 1][1];
                asm("v_permlane32_swap_b32 %0, %1" : "+v"(a0), "+v"(b0));
                asm("v_permlane16_swap_b32 %0, %1" : "+v"(a0), "+v"(b0));
                asm("v_permlane32_swap_b32 %0, %1" : "+v"(a1), "+v"(b1));
                asm("v_permlane16_swap_b32 %0, %1" : "+v"(a1), "+v"(b1));
                union { unsigned int u[4]; bf16x8 v; } cvt;
                cvt.u[0] = a0; cvt.u[1] = a1; cvt.u[2] = b0; cvt.u[3] = b1;
                bp[kk] = cvt.v;
            }

            // ---- O^T += V^T · P^T (swapped PV) ----
            __builtin_amdgcn_s_setprio(1);
            #pragma unroll
            for (int kk = 0; kk < 2; kk++)
                #pragma unroll
                for (int nt = 0; nt < 4; nt++) {
                    int row = nt * 16 + lr;
                    bf16x8 bv = *reinterpret_cast<const bf16x8*>(
                        Vs + row * 128 + (((kk * 4 + lg) * 16) ^ ((row & 7) << 4)));
                    accO[nt] = __builtin_amdgcn_mfma_f32_16x16x32_bf16(bv, bp[kk], accO[nt], 0, 0, 0);
                }
            __builtin_amdgcn_s_setprio(0);
        }

        // ---- stage next tile into LDS ----
        if (kb < kbmax) {
            __syncthreads();
            *reinterpret_cast<bf16x8*>(Ksh + r * 128 + sw) = pkh;
            *reinterpret_cast<bf16x8*>(Ksl + r * 128 + sw) = pkl;
            *reinterpret_cast<bf16x8*>(Vs + r * 128 + sw) = pv;
            __syncthreads();
        }
    }

    // final cross-lane sum (2 steps) + packed epilogue
    float ps = lsum;
    ps += __shfl_xor(ps, 16);
    ps += __shfl_xor(ps, 32);
    float inv = 1.0f / ps;
    size_t rowbase = (size_t)((bh >> 4) * 2048 + qg) * 1024 + (bh & 15) * 64;
    #pragma unroll
    for (int nt = 0; nt < 4; nt++) {
        bf16x4 o;
        #pragma unroll
        for (int j = 0; j < 4; j++) o[j] = (bf16)(accO[nt][j] * inv);
        *reinterpret_cast<bf16x4*>(hd + rowbase + nt * 16 + 4 * lg) = o;
    }
}

// ---------------- launcher ----------------

extern "C" void kernel_launch(void* const* d_in, const int* in_sizes, int n_in,
                              void* d_out, int out_size, void* d_ws, size_t ws_size,
                              hipStream_t stream) {
    const float* x  = (const float*)d_in[0];
    const float* Wq = (const float*)d_in[1];
    const float* Wk = (const float*)d_in[2];
    const float* Wv = (const float*)d_in[3];
    const float* W0 = (const float*)d_in[4];
    float* out = (float*)d_out;

    char* ws = (char*)d_ws;
    bf16* w0t = (bf16*)(ws + 0);
    bf16* Qhi = (bf16*)(ws + 2097152);
    bf16* Qlo = (bf16*)(ws + 18874368);
    bf16* Khi = (bf16*)(ws + 35651584);
    bf16* Klo = (bf16*)(ws + 52428800);
    bf16* Vtb = (bf16*)(ws + 69206016);
    bf16* whi = (bf16*)(ws + 85983232);
    bf16* wlo = (bf16*)(ws + 92274688);
    bf16* hd  = (bf16*)(ws + 85983232);
    if (ws_size < 102760448u) return;  // need 98 MiB scratch

    k_cvt_wqkv<<<dim3(16, 16, 3), 256, 0, stream>>>(Wq, Wk, Wv, whi, wlo);
    k_cvt_w0  <<<dim3(16, 16), 256, 0, stream>>>(W0, w0t);
    k_gemm3   <<<dim3(64, 16), 256, 0, stream>>>(x, whi, wlo, Qhi, Qlo, Khi, Klo);
    k_gemmV   <<<dim3(64, 8), 256, 0, stream>>>(x, whi, Vtb);
    k_attn    <<<1024, 512, 0, stream>>>(Qhi, Qlo, Khi, Klo, Vtb, hd);
    k_gemm1   <<<dim3(64, 8), 256, 0, stream>>>(hd, w0t, out);
}